// Round 5
// baseline (2292.275 us; speedup 1.0000x reference)
//
#include <hip/hip_runtime.h>
#include <math.h>

// ---------------------------------------------------------------------------
// StageA GNN: encoder -> CSR build -> L x (gate, agg+update+LN) -> head
// R5: (a) enc_kernel: no LDS (W1/W2 via L1/L2), 8 rows/wave -> occupancy up,
// 8 indep FMA chains; (b) gate-projection (a/bb for next layer) fused as an
// epilogue into h's producer (enc for layer 0, agg_update l=0 for layer 1)
// -> both gateproj dispatches and their h re-reads eliminated.
// ---------------------------------------------------------------------------

typedef unsigned short ushort_t;

__device__ __forceinline__ float bf2f(ushort_t u) {
    return __uint_as_float(((unsigned int)u) << 16);
}
__device__ __forceinline__ ushort_t f2bf(float f) {
    unsigned int x = __float_as_uint(f);
    unsigned int lsb = (x >> 16) & 1u;
    x += 0x7fffu + lsb;                 // round-to-nearest-even
    return (ushort_t)(x >> 16);
}

__device__ __forceinline__ float wave_sum64(float v) {
    #pragma unroll
    for (int o = 32; o > 0; o >>= 1) v += __shfl_xor(v, o, 64);
    return v;
}

// h = relu(relu(x@W1+b1)@W2+b2); 8 rows/wave, weights via L1/L2 (no LDS).
// Epilogue: ab = bf16(h@gw1[0:64]+gb1), bbuf = h@gw1[64:128].
__global__ __launch_bounds__(256) void enc_kernel(
    const float* __restrict__ x, const float* __restrict__ w1,
    const float* __restrict__ b1, const float* __restrict__ w2,
    const float* __restrict__ b2,
    const float* __restrict__ gw1, const float* __restrict__ gb1,
    float* __restrict__ h, ushort_t* __restrict__ hb,
    ushort_t* __restrict__ ab, float* __restrict__ bbuf,
    int N, int C) {
    const int lane = threadIdx.x & 63;
    const int wid  = blockIdx.x * (blockDim.x >> 6) + (threadIdx.x >> 6);
    const int nw   = gridDim.x * (blockDim.x >> 6);
    const float b1l = b1[lane], b2l = b2[lane];
    const float gbl = gb1[lane];
    const int noct = (N + 7) >> 3;
    for (int q = wid; q < noct; q += nw) {
        const int r0 = q * 8;
        if (r0 + 7 < N) {
            const float* xr = x + (size_t)r0 * C;
            float s0 = 0.f, s1 = 0.f, s2 = 0.f, s3 = 0.f;
            float s4 = 0.f, s5 = 0.f, s6 = 0.f, s7 = 0.f;
            for (int k4 = 0; k4 < C / 4; ++k4) {
                const float* wp = w1 + (size_t)k4 * 256 + lane;
                float wa = wp[0], wbv = wp[64], wc = wp[128], wd = wp[192];
                #define ENC_STEP(J) { \
                    float4 v = *(const float4*)(xr + (size_t)(J) * C + k4 * 4); \
                    s##J = fmaf(wa,  v.x, s##J); \
                    s##J = fmaf(wbv, v.y, s##J); \
                    s##J = fmaf(wc,  v.z, s##J); \
                    s##J = fmaf(wd,  v.w, s##J); }
                ENC_STEP(0) ENC_STEP(1) ENC_STEP(2) ENC_STEP(3)
                ENC_STEP(4) ENC_STEP(5) ENC_STEP(6) ENC_STEP(7)
                #undef ENC_STEP
            }
            float t0 = fmaxf(s0 + b1l, 0.f), t1 = fmaxf(s1 + b1l, 0.f);
            float t2 = fmaxf(s2 + b1l, 0.f), t3 = fmaxf(s3 + b1l, 0.f);
            float t4 = fmaxf(s4 + b1l, 0.f), t5 = fmaxf(s5 + b1l, 0.f);
            float t6 = fmaxf(s6 + b1l, 0.f), t7 = fmaxf(s7 + b1l, 0.f);
            float c0 = 0.f, c1 = 0.f, c2 = 0.f, c3 = 0.f;
            float c4 = 0.f, c5 = 0.f, c6 = 0.f, c7 = 0.f;
            #pragma unroll
            for (int k = 0; k < 64; ++k) {
                float wv = w2[(size_t)k * 64 + lane];
                c0 = fmaf(wv, __shfl(t0, k, 64), c0);
                c1 = fmaf(wv, __shfl(t1, k, 64), c1);
                c2 = fmaf(wv, __shfl(t2, k, 64), c2);
                c3 = fmaf(wv, __shfl(t3, k, 64), c3);
                c4 = fmaf(wv, __shfl(t4, k, 64), c4);
                c5 = fmaf(wv, __shfl(t5, k, 64), c5);
                c6 = fmaf(wv, __shfl(t6, k, 64), c6);
                c7 = fmaf(wv, __shfl(t7, k, 64), c7);
            }
            float h0 = fmaxf(c0 + b2l, 0.f), h1 = fmaxf(c1 + b2l, 0.f);
            float h2 = fmaxf(c2 + b2l, 0.f), h3 = fmaxf(c3 + b2l, 0.f);
            float h4 = fmaxf(c4 + b2l, 0.f), h5 = fmaxf(c5 + b2l, 0.f);
            float h6 = fmaxf(c6 + b2l, 0.f), h7 = fmaxf(c7 + b2l, 0.f);
            #define ENC_STORE(J) { \
                h[(size_t)(r0 + (J)) * 64 + lane] = h##J; \
                hb[(size_t)(r0 + (J)) * 64 + lane] = f2bf(h##J); }
            ENC_STORE(0) ENC_STORE(1) ENC_STORE(2) ENC_STORE(3)
            ENC_STORE(4) ENC_STORE(5) ENC_STORE(6) ENC_STORE(7)
            #undef ENC_STORE
            // ---- fused gate projection for layer 0 ----
            float pa0 = 0.f, pa1 = 0.f, pa2 = 0.f, pa3 = 0.f;
            float pa4 = 0.f, pa5 = 0.f, pa6 = 0.f, pa7 = 0.f;
            float pb0 = 0.f, pb1 = 0.f, pb2 = 0.f, pb3 = 0.f;
            float pb4 = 0.f, pb5 = 0.f, pb6 = 0.f, pb7 = 0.f;
            #pragma unroll
            for (int k = 0; k < 64; ++k) {
                float ga  = gw1[(size_t)k * 64 + lane];
                float gbv = gw1[(size_t)(64 + k) * 64 + lane];
                #define PROJ_STEP(J) { \
                    float tv = __shfl(h##J, k, 64); \
                    pa##J = fmaf(ga,  tv, pa##J); \
                    pb##J = fmaf(gbv, tv, pb##J); }
                PROJ_STEP(0) PROJ_STEP(1) PROJ_STEP(2) PROJ_STEP(3)
                PROJ_STEP(4) PROJ_STEP(5) PROJ_STEP(6) PROJ_STEP(7)
                #undef PROJ_STEP
            }
            #define PROJ_STORE(J) { \
                ab[(size_t)(r0 + (J)) * 64 + lane] = f2bf(pa##J + gbl); \
                bbuf[(size_t)(r0 + (J)) * 64 + lane] = pb##J; }
            PROJ_STORE(0) PROJ_STORE(1) PROJ_STORE(2) PROJ_STORE(3)
            PROJ_STORE(4) PROJ_STORE(5) PROJ_STORE(6) PROJ_STORE(7)
            #undef PROJ_STORE
        } else {
            for (int r = r0; r < N; ++r) {
                const float* xr = x + (size_t)r * C;
                float acc = 0.f;
                for (int k4 = 0; k4 < C / 4; ++k4) {
                    const float* wp = w1 + (size_t)k4 * 256 + lane;
                    float4 v = *(const float4*)(xr + k4 * 4);
                    acc = fmaf(wp[0],   v.x, acc);
                    acc = fmaf(wp[64],  v.y, acc);
                    acc = fmaf(wp[128], v.z, acc);
                    acc = fmaf(wp[192], v.w, acc);
                }
                float t = fmaxf(acc + b1l, 0.f);
                float acc2 = 0.f;
                #pragma unroll
                for (int k = 0; k < 64; ++k)
                    acc2 = fmaf(w2[(size_t)k * 64 + lane], __shfl(t, k, 64), acc2);
                float hv = fmaxf(acc2 + b2l, 0.f);
                h[(size_t)r * 64 + lane] = hv;
                hb[(size_t)r * 64 + lane] = f2bf(hv);
                float aa = 0.f, bv = 0.f;
                #pragma unroll
                for (int k = 0; k < 64; ++k) {
                    float tv = __shfl(hv, k, 64);
                    aa = fmaf(gw1[(size_t)k * 64 + lane], tv, aa);
                    bv = fmaf(gw1[(size_t)(64 + k) * 64 + lane], tv, bv);
                }
                ab[(size_t)r * 64 + lane] = f2bf(aa + gbl);
                bbuf[(size_t)r * 64 + lane] = bv;
            }
        }
    }
}

// ---- CSR build (once per call, reused by both layers) ----
__global__ __launch_bounds__(256) void hist_kernel(
    const int* __restrict__ dst, int* __restrict__ cnt, int E) {
    for (int e = blockIdx.x * blockDim.x + threadIdx.x; e < E;
         e += gridDim.x * blockDim.x)
        atomicAdd(&cnt[dst[e]], 1);
}

// single-block exclusive scan: cnt[N] -> row_ptr[N+1]
__global__ __launch_bounds__(1024) void scan_kernel(
    const int* __restrict__ cnt, int* __restrict__ row_ptr, int N) {
    __shared__ int sums[1024];
    const int tid = threadIdx.x;
    const int chunk = (N + 1023) / 1024;
    const int beg = tid * chunk;
    const int end = min(beg + chunk, N);
    int s = 0;
    for (int i = beg; i < end; ++i) s += cnt[i];
    sums[tid] = s;
    __syncthreads();
    for (int off = 1; off < 1024; off <<= 1) {
        int v = (tid >= off) ? sums[tid - off] : 0;
        __syncthreads();
        sums[tid] += v;
        __syncthreads();
    }
    int run = (tid == 0) ? 0 : sums[tid - 1];
    for (int i = beg; i < end; ++i) {
        row_ptr[i] = run;
        run += cnt[i];
    }
    if (tid == 1023) row_ptr[N] = sums[1023];
}

// fill dst-grouped records: (src, dst, base_w*sig(rr_s)*sig(rr_d), pad)
__global__ __launch_bounds__(256) void scatter_kernel(
    const int* __restrict__ src, const int* __restrict__ dst,
    const float* __restrict__ base_w, const float* __restrict__ rr,
    const int* __restrict__ row_ptr, int* __restrict__ fill,
    int4* __restrict__ recs, int E) {
    for (int e = blockIdx.x * blockDim.x + threadIdx.x; e < E;
         e += gridDim.x * blockDim.x) {
        int s = src[e], d = dst[e];
        int pos = row_ptr[d] + atomicAdd(&fill[d], 1);
        float rs = 1.f / (1.f + __expf(-rr[s]));
        float rd = 1.f / (1.f + __expf(-rr[d]));
        float c = base_w[e] * rs * rd;
        recs[pos] = make_int4(s, d, __float_as_int(c), 0);
    }
}

// 16 lanes per edge: z = relu(a[s]+bb[d]) dot gw2 (4 elems/lane, 4-step reduce)
// w = c * sigmoid(z + gb2);  sw[e] = (s, w).  a gathered as bf16 (8B/lane).
__global__ __launch_bounds__(256) void gate_kernel(
    const int4* __restrict__ recs, const ushort_t* __restrict__ ab,
    const float* __restrict__ bb, const float* __restrict__ gw2,
    const float* __restrict__ gb2, int2* __restrict__ sw, int E) {
    const int lane = threadIdx.x & 63;
    const int sub  = lane & 15;                       // feature slice id
    const float4 gv = ((const float4*)gw2)[sub];
    const float gb = gb2[0];
    int grp  = (blockIdx.x * blockDim.x + threadIdx.x) >> 4;
    const int ngrp = (gridDim.x * blockDim.x) >> 4;
    for (int e = grp; e < E; e += ngrp) {
        int4 r = recs[e];                             // broadcast within group
        ushort4 av = ((const ushort4*)(ab + (size_t)r.x * 64))[sub];
        float4 bv = ((const float4*)(bb + (size_t)r.y * 64))[sub];
        float t = fmaxf(bf2f(av.x) + bv.x, 0.f) * gv.x
                + fmaxf(bf2f(av.y) + bv.y, 0.f) * gv.y
                + fmaxf(bf2f(av.z) + bv.z, 0.f) * gv.z
                + fmaxf(bf2f(av.w) + bv.w, 0.f) * gv.w;
        #pragma unroll
        for (int o = 8; o > 0; o >>= 1) t += __shfl_xor(t, o, 64);
        float w = __int_as_float(r.z) / (1.f + __expf(-(t + gb)));
        if (sub == 0) sw[e] = make_int2(r.x, __float_as_int(w));
    }
}

// wave-per-node: gather+fma aggregation over bf16 h rows, fused update MLP +
// LayerNorm in fp32. Optional epilogue: gate projection for the next layer
// (gw1 != nullptr): ab = bf16(hn@gw1[0:64]+gb1), bbuf = hn@gw1[64:128].
__global__ __launch_bounds__(256) void agg_update_kernel(
    const int* __restrict__ row_ptr, const int2* __restrict__ sw,
    const ushort_t* __restrict__ hb_in, const float* __restrict__ h_in,
    const float* __restrict__ w1, const float* __restrict__ b1,
    const float* __restrict__ w2, const float* __restrict__ b2,
    const float* __restrict__ lng, const float* __restrict__ lnb,
    const float* __restrict__ gw1, const float* __restrict__ gb1,
    float* __restrict__ h_out, ushort_t* __restrict__ hb_out,
    ushort_t* __restrict__ ab, float* __restrict__ bbuf, int N) {
    __shared__ float ws1[64 * 64], ws2[64 * 64];  // 16 + 16 KB
    for (int i = threadIdx.x; i < 4096; i += blockDim.x) {
        ws1[i] = w1[i];
        ws2[i] = w2[i];
    }
    __syncthreads();
    const int lane = threadIdx.x & 63;
    const int wid  = blockIdx.x * (blockDim.x >> 6) + (threadIdx.x >> 6);
    const int nw   = gridDim.x * (blockDim.x >> 6);
    const float b1l = b1[lane], b2l = b2[lane];
    const float gl = lng[lane], bl = lnb[lane];
    const bool do_proj = (gw1 != nullptr);
    const float gbl = do_proj ? gb1[lane] : 0.f;
    for (int n = wid; n < N; n += nw) {
        const int beg = row_ptr[n], end = row_ptr[n + 1];
        float macc = 0.f, dacc = 0.f;
        int i = beg;
        for (; i + 4 <= end; i += 4) {
            int2 r0 = sw[i], r1 = sw[i + 1], r2 = sw[i + 2], r3 = sw[i + 3];
            float hv0 = bf2f(hb_in[(size_t)r0.x * 64 + lane]);
            float hv1 = bf2f(hb_in[(size_t)r1.x * 64 + lane]);
            float hv2 = bf2f(hb_in[(size_t)r2.x * 64 + lane]);
            float hv3 = bf2f(hb_in[(size_t)r3.x * 64 + lane]);
            float w0 = __int_as_float(r0.y), w1v = __int_as_float(r1.y);
            float w2v = __int_as_float(r2.y), w3v = __int_as_float(r3.y);
            macc = fmaf(w0, hv0, macc);
            macc = fmaf(w1v, hv1, macc);
            macc = fmaf(w2v, hv2, macc);
            macc = fmaf(w3v, hv3, macc);
            dacc += (w0 + w1v) + (w2v + w3v);
        }
        for (; i < end; ++i) {
            int2 r0 = sw[i];
            float hv0 = bf2f(hb_in[(size_t)r0.x * 64 + lane]);
            float w0 = __int_as_float(r0.y);
            macc = fmaf(w0, hv0, macc);
            dacc += w0;
        }
        // ---- fused update MLP + LayerNorm ----
        float neigh = macc / (dacc + 1e-8f);
        float acc = 0.f;
        #pragma unroll
        for (int k = 0; k < 64; ++k) {
            float tv = __shfl(neigh, k, 64);
            acc = fmaf(ws1[k * 64 + lane], tv, acc);
        }
        float t = fmaxf(acc + b1l, 0.f);
        float acc2 = 0.f;
        #pragma unroll
        for (int k = 0; k < 64; ++k) {
            float tv = __shfl(t, k, 64);
            acc2 = fmaf(ws2[k * 64 + lane], tv, acc2);
        }
        float pre = h_in[(size_t)n * 64 + lane] + acc2 + b2l;
        float s1 = wave_sum64(pre);
        float s2 = wave_sum64(pre * pre);
        float mean = s1 * (1.0f / 64.0f);
        float var  = s2 * (1.0f / 64.0f) - mean * mean;
        float hn = (pre - mean) * rsqrtf(var + 1e-5f) * gl + bl;
        h_out[(size_t)n * 64 + lane] = hn;
        hb_out[(size_t)n * 64 + lane] = f2bf(hn);
        if (do_proj) {
            float aa = 0.f, bv = 0.f;
            #pragma unroll
            for (int k = 0; k < 64; ++k) {
                float tv = __shfl(hn, k, 64);
                aa = fmaf(gw1[(size_t)k * 64 + lane], tv, aa);
                bv = fmaf(gw1[(size_t)(64 + k) * 64 + lane], tv, bv);
            }
            ab[(size_t)n * 64 + lane] = f2bf(aa + gbl);
            bbuf[(size_t)n * 64 + lane] = bv;
        }
    }
}

// U = softplus(h @ toU_w + toU_b), K=32
__global__ __launch_bounds__(256) void out_kernel(
    const float* __restrict__ h, const float* __restrict__ tw,
    const float* __restrict__ tb, float* __restrict__ U, int N) {
    int gid = blockIdx.x * blockDim.x + threadIdx.x;
    int n = gid >> 5;
    int k = gid & 31;
    if (n >= N) return;
    float acc = tb[k];
    const float* hr = h + (size_t)n * 64;
    #pragma unroll 8
    for (int j = 0; j < 64; ++j) acc = fmaf(hr[j], tw[j * 32 + k], acc);
    float sp = acc > 0.f ? acc + log1pf(__expf(-acc)) : log1pf(__expf(acc));
    U[(size_t)n * 32 + k] = sp;
}

extern "C" void kernel_launch(void* const* d_in, const int* in_sizes, int n_in,
                              void* d_out, int out_size, void* d_ws, size_t ws_size,
                              hipStream_t stream) {
    const float* x       = (const float*)d_in[0];
    const int*   src     = (const int*)d_in[1];
    const int*   dst     = (const int*)d_in[2];
    const float* base_w  = (const float*)d_in[3];
    const float* enc_w1  = (const float*)d_in[4];
    const float* enc_b1  = (const float*)d_in[5];
    const float* enc_w2  = (const float*)d_in[6];
    const float* enc_b2  = (const float*)d_in[7];
    const float* gate_w1 = (const float*)d_in[8];
    const float* gate_b1 = (const float*)d_in[9];
    const float* gate_w2 = (const float*)d_in[10];
    const float* gate_b2 = (const float*)d_in[11];
    const float* upd_w1  = (const float*)d_in[12];
    const float* upd_b1  = (const float*)d_in[13];
    const float* upd_w2  = (const float*)d_in[14];
    const float* upd_b2  = (const float*)d_in[15];
    const float* ln_g    = (const float*)d_in[16];
    const float* ln_b    = (const float*)d_in[17];
    const float* rho_raw = (const float*)d_in[18];
    const float* toU_w   = (const float*)d_in[19];
    const float* toU_b   = (const float*)d_in[20];

    const int N = in_sizes[18];          // 50000
    const int C = in_sizes[0] / N;       // 256
    const int E = in_sizes[1];           // 800000
    const int L = 2;

    // workspace layout (float units), sections padded to 16B alignment
    float* ws  = (float*)d_ws;
    size_t off = 0;
    float* h0  = ws + off; off += (size_t)N * 64;
    float* h1  = ws + off; off += (size_t)N * 64;
    ushort_t* hb0 = (ushort_t*)(ws + off); off += (size_t)N * 32;
    ushort_t* hb1 = (ushort_t*)(ws + off); off += (size_t)N * 32;
    ushort_t* ab  = (ushort_t*)(ws + off); off += (size_t)N * 32;
    float* bb  = ws + off; off += (size_t)N * 64;
    int* row_ptr = (int*)(ws + off); off += (size_t)((N + 1 + 3) & ~3);
    int* cnt     = (int*)(ws + off); off += (size_t)((N + 3) & ~3);
    int4* recs   = (int4*)(ws + off); off += (size_t)E * 4;   // (s,d,c,0)
    int2* sw     = (int2*)(ws + off); off += (size_t)E * 2;   // (s,w)

    // encoder (+ fused layer-0 gate projection)
    enc_kernel<<<1563, 256, 0, stream>>>(x, enc_w1, enc_b1, enc_w2, enc_b2,
                                         gate_w1, gate_b1,
                                         h0, hb0, ab, bb, N, C);

    // CSR build (dst-sorted edge records); rho folded into scatter
    hipMemsetAsync(cnt, 0, (size_t)N * sizeof(int), stream);
    hist_kernel<<<(E + 255) / 256, 256, 0, stream>>>(dst, cnt, E);
    scan_kernel<<<1, 1024, 0, stream>>>(cnt, row_ptr, N);
    hipMemsetAsync(cnt, 0, (size_t)N * sizeof(int), stream);
    scatter_kernel<<<(E + 255) / 256, 256, 0, stream>>>(src, dst, base_w, rho_raw,
                                                        row_ptr, cnt, recs, E);

    float* h_cur = h0;  ushort_t* hb_cur = hb0;
    float* h_nxt = h1;  ushort_t* hb_nxt = hb1;
    for (int l = 0; l < L; ++l) {
        const bool last = (l == L - 1);
        gate_kernel<<<4096, 256, 0, stream>>>(recs, ab, bb, gate_w2, gate_b2, sw, E);
        agg_update_kernel<<<2048, 256, 0, stream>>>(
            row_ptr, sw, hb_cur, h_cur,
            upd_w1 + (size_t)l * 4096, upd_b1 + l * 64,
            upd_w2 + (size_t)l * 4096, upd_b2 + l * 64,
            ln_g + l * 64, ln_b + l * 64,
            last ? nullptr : gate_w1, last ? nullptr : gate_b1,
            h_nxt, hb_nxt, ab, bb, N);
        float* tf = h_cur; h_cur = h_nxt; h_nxt = tf;
        ushort_t* tb2 = hb_cur; hb_cur = hb_nxt; hb_nxt = tb2;
    }

    out_kernel<<<((N * 32) + 255) / 256, 256, 0, stream>>>(h_cur, toU_w, toU_b,
                                                           (float*)d_out, N);
}

// Round 6
// 1263.814 us; speedup vs baseline: 1.8138x; 1.8138x over previous
//
#include <hip/hip_runtime.h>
#include <math.h>

// ---------------------------------------------------------------------------
// StageA GNN: encoder -> CSR build -> L x (gate, agg+update+LN) -> head
// R6: revert R5's proj-fusion into agg_update (VGPR 228 -> occupancy collapse);
// agg_update is lean again (no LDS, weights via L1, 8-deep gather unroll).
// Keep R5's enc (no LDS, 8 rows/wave, fused layer-0 gate projection).
// Standalone lean gateproj for layer 1.
// ---------------------------------------------------------------------------

typedef unsigned short ushort_t;

__device__ __forceinline__ float bf2f(ushort_t u) {
    return __uint_as_float(((unsigned int)u) << 16);
}
__device__ __forceinline__ ushort_t f2bf(float f) {
    unsigned int x = __float_as_uint(f);
    unsigned int lsb = (x >> 16) & 1u;
    x += 0x7fffu + lsb;                 // round-to-nearest-even
    return (ushort_t)(x >> 16);
}

__device__ __forceinline__ float wave_sum64(float v) {
    #pragma unroll
    for (int o = 32; o > 0; o >>= 1) v += __shfl_xor(v, o, 64);
    return v;
}

// h = relu(relu(x@W1+b1)@W2+b2); 8 rows/wave, weights via L1/L2 (no LDS).
// Epilogue: ab = bf16(h@gw1[0:64]+gb1), bbuf = h@gw1[64:128].
__global__ __launch_bounds__(256) void enc_kernel(
    const float* __restrict__ x, const float* __restrict__ w1,
    const float* __restrict__ b1, const float* __restrict__ w2,
    const float* __restrict__ b2,
    const float* __restrict__ gw1, const float* __restrict__ gb1,
    float* __restrict__ h, ushort_t* __restrict__ hb,
    ushort_t* __restrict__ ab, float* __restrict__ bbuf,
    int N, int C) {
    const int lane = threadIdx.x & 63;
    const int wid  = blockIdx.x * (blockDim.x >> 6) + (threadIdx.x >> 6);
    const int nw   = gridDim.x * (blockDim.x >> 6);
    const float b1l = b1[lane], b2l = b2[lane];
    const float gbl = gb1[lane];
    const int noct = (N + 7) >> 3;
    for (int q = wid; q < noct; q += nw) {
        const int r0 = q * 8;
        if (r0 + 7 < N) {
            const float* xr = x + (size_t)r0 * C;
            float s0 = 0.f, s1 = 0.f, s2 = 0.f, s3 = 0.f;
            float s4 = 0.f, s5 = 0.f, s6 = 0.f, s7 = 0.f;
            for (int k4 = 0; k4 < C / 4; ++k4) {
                const float* wp = w1 + (size_t)k4 * 256 + lane;
                float wa = wp[0], wbv = wp[64], wc = wp[128], wd = wp[192];
                #define ENC_STEP(J) { \
                    float4 v = *(const float4*)(xr + (size_t)(J) * C + k4 * 4); \
                    s##J = fmaf(wa,  v.x, s##J); \
                    s##J = fmaf(wbv, v.y, s##J); \
                    s##J = fmaf(wc,  v.z, s##J); \
                    s##J = fmaf(wd,  v.w, s##J); }
                ENC_STEP(0) ENC_STEP(1) ENC_STEP(2) ENC_STEP(3)
                ENC_STEP(4) ENC_STEP(5) ENC_STEP(6) ENC_STEP(7)
                #undef ENC_STEP
            }
            float t0 = fmaxf(s0 + b1l, 0.f), t1 = fmaxf(s1 + b1l, 0.f);
            float t2 = fmaxf(s2 + b1l, 0.f), t3 = fmaxf(s3 + b1l, 0.f);
            float t4 = fmaxf(s4 + b1l, 0.f), t5 = fmaxf(s5 + b1l, 0.f);
            float t6 = fmaxf(s6 + b1l, 0.f), t7 = fmaxf(s7 + b1l, 0.f);
            float c0 = 0.f, c1 = 0.f, c2 = 0.f, c3 = 0.f;
            float c4 = 0.f, c5 = 0.f, c6 = 0.f, c7 = 0.f;
            #pragma unroll
            for (int k = 0; k < 64; ++k) {
                float wv = w2[(size_t)k * 64 + lane];
                c0 = fmaf(wv, __shfl(t0, k, 64), c0);
                c1 = fmaf(wv, __shfl(t1, k, 64), c1);
                c2 = fmaf(wv, __shfl(t2, k, 64), c2);
                c3 = fmaf(wv, __shfl(t3, k, 64), c3);
                c4 = fmaf(wv, __shfl(t4, k, 64), c4);
                c5 = fmaf(wv, __shfl(t5, k, 64), c5);
                c6 = fmaf(wv, __shfl(t6, k, 64), c6);
                c7 = fmaf(wv, __shfl(t7, k, 64), c7);
            }
            float h0 = fmaxf(c0 + b2l, 0.f), h1 = fmaxf(c1 + b2l, 0.f);
            float h2 = fmaxf(c2 + b2l, 0.f), h3 = fmaxf(c3 + b2l, 0.f);
            float h4 = fmaxf(c4 + b2l, 0.f), h5 = fmaxf(c5 + b2l, 0.f);
            float h6 = fmaxf(c6 + b2l, 0.f), h7 = fmaxf(c7 + b2l, 0.f);
            #define ENC_STORE(J) { \
                h[(size_t)(r0 + (J)) * 64 + lane] = h##J; \
                hb[(size_t)(r0 + (J)) * 64 + lane] = f2bf(h##J); }
            ENC_STORE(0) ENC_STORE(1) ENC_STORE(2) ENC_STORE(3)
            ENC_STORE(4) ENC_STORE(5) ENC_STORE(6) ENC_STORE(7)
            #undef ENC_STORE
            // ---- fused gate projection for layer 0 ----
            float pa0 = 0.f, pa1 = 0.f, pa2 = 0.f, pa3 = 0.f;
            float pa4 = 0.f, pa5 = 0.f, pa6 = 0.f, pa7 = 0.f;
            float pb0 = 0.f, pb1 = 0.f, pb2 = 0.f, pb3 = 0.f;
            float pb4 = 0.f, pb5 = 0.f, pb6 = 0.f, pb7 = 0.f;
            #pragma unroll
            for (int k = 0; k < 64; ++k) {
                float ga  = gw1[(size_t)k * 64 + lane];
                float gbv = gw1[(size_t)(64 + k) * 64 + lane];
                #define PROJ_STEP(J) { \
                    float tv = __shfl(h##J, k, 64); \
                    pa##J = fmaf(ga,  tv, pa##J); \
                    pb##J = fmaf(gbv, tv, pb##J); }
                PROJ_STEP(0) PROJ_STEP(1) PROJ_STEP(2) PROJ_STEP(3)
                PROJ_STEP(4) PROJ_STEP(5) PROJ_STEP(6) PROJ_STEP(7)
                #undef PROJ_STEP
            }
            #define PROJ_STORE(J) { \
                ab[(size_t)(r0 + (J)) * 64 + lane] = f2bf(pa##J + gbl); \
                bbuf[(size_t)(r0 + (J)) * 64 + lane] = pb##J; }
            PROJ_STORE(0) PROJ_STORE(1) PROJ_STORE(2) PROJ_STORE(3)
            PROJ_STORE(4) PROJ_STORE(5) PROJ_STORE(6) PROJ_STORE(7)
            #undef PROJ_STORE
        } else {
            for (int r = r0; r < N; ++r) {
                const float* xr = x + (size_t)r * C;
                float acc = 0.f;
                for (int k4 = 0; k4 < C / 4; ++k4) {
                    const float* wp = w1 + (size_t)k4 * 256 + lane;
                    float4 v = *(const float4*)(xr + k4 * 4);
                    acc = fmaf(wp[0],   v.x, acc);
                    acc = fmaf(wp[64],  v.y, acc);
                    acc = fmaf(wp[128], v.z, acc);
                    acc = fmaf(wp[192], v.w, acc);
                }
                float t = fmaxf(acc + b1l, 0.f);
                float acc2 = 0.f;
                #pragma unroll
                for (int k = 0; k < 64; ++k)
                    acc2 = fmaf(w2[(size_t)k * 64 + lane], __shfl(t, k, 64), acc2);
                float hv = fmaxf(acc2 + b2l, 0.f);
                h[(size_t)r * 64 + lane] = hv;
                hb[(size_t)r * 64 + lane] = f2bf(hv);
                float aa = 0.f, bv = 0.f;
                #pragma unroll
                for (int k = 0; k < 64; ++k) {
                    float tv = __shfl(hv, k, 64);
                    aa = fmaf(gw1[(size_t)k * 64 + lane], tv, aa);
                    bv = fmaf(gw1[(size_t)(64 + k) * 64 + lane], tv, bv);
                }
                ab[(size_t)r * 64 + lane] = f2bf(aa + gbl);
                bbuf[(size_t)r * 64 + lane] = bv;
            }
        }
    }
}

// ---- CSR build (once per call, reused by both layers) ----
__global__ __launch_bounds__(256) void hist_kernel(
    const int* __restrict__ dst, int* __restrict__ cnt, int E) {
    for (int e = blockIdx.x * blockDim.x + threadIdx.x; e < E;
         e += gridDim.x * blockDim.x)
        atomicAdd(&cnt[dst[e]], 1);
}

// single-block exclusive scan: cnt[N] -> row_ptr[N+1]
__global__ __launch_bounds__(1024) void scan_kernel(
    const int* __restrict__ cnt, int* __restrict__ row_ptr, int N) {
    __shared__ int sums[1024];
    const int tid = threadIdx.x;
    const int chunk = (N + 1023) / 1024;
    const int beg = tid * chunk;
    const int end = min(beg + chunk, N);
    int s = 0;
    for (int i = beg; i < end; ++i) s += cnt[i];
    sums[tid] = s;
    __syncthreads();
    for (int off = 1; off < 1024; off <<= 1) {
        int v = (tid >= off) ? sums[tid - off] : 0;
        __syncthreads();
        sums[tid] += v;
        __syncthreads();
    }
    int run = (tid == 0) ? 0 : sums[tid - 1];
    for (int i = beg; i < end; ++i) {
        row_ptr[i] = run;
        run += cnt[i];
    }
    if (tid == 1023) row_ptr[N] = sums[1023];
}

// fill dst-grouped records: (src, dst, base_w*sig(rr_s)*sig(rr_d), pad)
__global__ __launch_bounds__(256) void scatter_kernel(
    const int* __restrict__ src, const int* __restrict__ dst,
    const float* __restrict__ base_w, const float* __restrict__ rr,
    const int* __restrict__ row_ptr, int* __restrict__ fill,
    int4* __restrict__ recs, int E) {
    for (int e = blockIdx.x * blockDim.x + threadIdx.x; e < E;
         e += gridDim.x * blockDim.x) {
        int s = src[e], d = dst[e];
        int pos = row_ptr[d] + atomicAdd(&fill[d], 1);
        float rs = 1.f / (1.f + __expf(-rr[s]));
        float rd = 1.f / (1.f + __expf(-rr[d]));
        float c = base_w[e] * rs * rd;
        recs[pos] = make_int4(s, d, __float_as_int(c), 0);
    }
}

// standalone gate projection (layer 1): ab/bbuf from h; weights via L1.
__global__ __launch_bounds__(256) void gateproj_kernel(
    const float* __restrict__ h, const float* __restrict__ gw1,
    const float* __restrict__ gb1, ushort_t* __restrict__ ab,
    float* __restrict__ bbuf, int N) {
    const int lane = threadIdx.x & 63;
    const int wid  = blockIdx.x * (blockDim.x >> 6) + (threadIdx.x >> 6);
    const int nw   = gridDim.x * (blockDim.x >> 6);
    const float gbl = gb1[lane];
    for (int r = wid; r < N; r += nw) {
        float hv = h[(size_t)r * 64 + lane];
        float aa = 0.f, bv = 0.f;
        #pragma unroll
        for (int k = 0; k < 64; ++k) {
            float tv = __shfl(hv, k, 64);
            aa = fmaf(gw1[(size_t)k * 64 + lane], tv, aa);
            bv = fmaf(gw1[(size_t)(64 + k) * 64 + lane], tv, bv);
        }
        ab[(size_t)r * 64 + lane] = f2bf(aa + gbl);
        bbuf[(size_t)r * 64 + lane] = bv;
    }
}

// 16 lanes per edge: z = relu(a[s]+bb[d]) dot gw2 (4 elems/lane, 4-step reduce)
// w = c * sigmoid(z + gb2);  sw[e] = (s, w).  a gathered as bf16 (8B/lane).
__global__ __launch_bounds__(256) void gate_kernel(
    const int4* __restrict__ recs, const ushort_t* __restrict__ ab,
    const float* __restrict__ bb, const float* __restrict__ gw2,
    const float* __restrict__ gb2, int2* __restrict__ sw, int E) {
    const int lane = threadIdx.x & 63;
    const int sub  = lane & 15;                       // feature slice id
    const float4 gv = ((const float4*)gw2)[sub];
    const float gb = gb2[0];
    int grp  = (blockIdx.x * blockDim.x + threadIdx.x) >> 4;
    const int ngrp = (gridDim.x * blockDim.x) >> 4;
    for (int e = grp; e < E; e += ngrp) {
        int4 r = recs[e];                             // broadcast within group
        ushort4 av = ((const ushort4*)(ab + (size_t)r.x * 64))[sub];
        float4 bv = ((const float4*)(bb + (size_t)r.y * 64))[sub];
        float t = fmaxf(bf2f(av.x) + bv.x, 0.f) * gv.x
                + fmaxf(bf2f(av.y) + bv.y, 0.f) * gv.y
                + fmaxf(bf2f(av.z) + bv.z, 0.f) * gv.z
                + fmaxf(bf2f(av.w) + bv.w, 0.f) * gv.w;
        #pragma unroll
        for (int o = 8; o > 0; o >>= 1) t += __shfl_xor(t, o, 64);
        float w = __int_as_float(r.z) / (1.f + __expf(-(t + gb)));
        if (sub == 0) sw[e] = make_int2(r.x, __float_as_int(w));
    }
}

// wave-per-node: gather+fma aggregation over bf16 h rows (8-deep unroll, no
// cross-lane ops in loop), fused update MLP + LayerNorm in fp32.
// Weights read from global (L1-resident) -> no LDS, no barrier.
__global__ __launch_bounds__(256) void agg_update_kernel(
    const int* __restrict__ row_ptr, const int2* __restrict__ sw,
    const ushort_t* __restrict__ hb_in, const float* __restrict__ h_in,
    const float* __restrict__ w1, const float* __restrict__ b1,
    const float* __restrict__ w2, const float* __restrict__ b2,
    const float* __restrict__ lng, const float* __restrict__ lnb,
    float* __restrict__ h_out, ushort_t* __restrict__ hb_out, int N) {
    const int lane = threadIdx.x & 63;
    const int wid  = blockIdx.x * (blockDim.x >> 6) + (threadIdx.x >> 6);
    const int nw   = gridDim.x * (blockDim.x >> 6);
    const float b1l = b1[lane], b2l = b2[lane];
    const float gl = lng[lane], bl = lnb[lane];
    for (int n = wid; n < N; n += nw) {
        const int beg = row_ptr[n], end = row_ptr[n + 1];
        float macc = 0.f, dacc = 0.f;
        int i = beg;
        for (; i + 8 <= end; i += 8) {
            int2 r0 = sw[i],     r1 = sw[i + 1], r2 = sw[i + 2], r3 = sw[i + 3];
            int2 r4 = sw[i + 4], r5 = sw[i + 5], r6 = sw[i + 6], r7 = sw[i + 7];
            float hv0 = bf2f(hb_in[(size_t)r0.x * 64 + lane]);
            float hv1 = bf2f(hb_in[(size_t)r1.x * 64 + lane]);
            float hv2 = bf2f(hb_in[(size_t)r2.x * 64 + lane]);
            float hv3 = bf2f(hb_in[(size_t)r3.x * 64 + lane]);
            float hv4 = bf2f(hb_in[(size_t)r4.x * 64 + lane]);
            float hv5 = bf2f(hb_in[(size_t)r5.x * 64 + lane]);
            float hv6 = bf2f(hb_in[(size_t)r6.x * 64 + lane]);
            float hv7 = bf2f(hb_in[(size_t)r7.x * 64 + lane]);
            float w0 = __int_as_float(r0.y), w1v = __int_as_float(r1.y);
            float w2v = __int_as_float(r2.y), w3v = __int_as_float(r3.y);
            float w4v = __int_as_float(r4.y), w5v = __int_as_float(r5.y);
            float w6v = __int_as_float(r6.y), w7v = __int_as_float(r7.y);
            macc = fmaf(w0, hv0, macc);  macc = fmaf(w1v, hv1, macc);
            macc = fmaf(w2v, hv2, macc); macc = fmaf(w3v, hv3, macc);
            macc = fmaf(w4v, hv4, macc); macc = fmaf(w5v, hv5, macc);
            macc = fmaf(w6v, hv6, macc); macc = fmaf(w7v, hv7, macc);
            dacc += ((w0 + w1v) + (w2v + w3v)) + ((w4v + w5v) + (w6v + w7v));
        }
        for (; i < end; ++i) {
            int2 r0 = sw[i];
            float hv0 = bf2f(hb_in[(size_t)r0.x * 64 + lane]);
            float w0 = __int_as_float(r0.y);
            macc = fmaf(w0, hv0, macc);
            dacc += w0;
        }
        // ---- fused update MLP + LayerNorm ----
        float neigh = macc / (dacc + 1e-8f);
        float acc = 0.f;
        #pragma unroll
        for (int k = 0; k < 64; ++k) {
            float tv = __shfl(neigh, k, 64);
            acc = fmaf(w1[(size_t)k * 64 + lane], tv, acc);
        }
        float t = fmaxf(acc + b1l, 0.f);
        float acc2 = 0.f;
        #pragma unroll
        for (int k = 0; k < 64; ++k) {
            float tv = __shfl(t, k, 64);
            acc2 = fmaf(w2[(size_t)k * 64 + lane], tv, acc2);
        }
        float pre = h_in[(size_t)n * 64 + lane] + acc2 + b2l;
        float s1 = wave_sum64(pre);
        float s2 = wave_sum64(pre * pre);
        float mean = s1 * (1.0f / 64.0f);
        float var  = s2 * (1.0f / 64.0f) - mean * mean;
        float hn = (pre - mean) * rsqrtf(var + 1e-5f) * gl + bl;
        h_out[(size_t)n * 64 + lane] = hn;
        hb_out[(size_t)n * 64 + lane] = f2bf(hn);
    }
}

// U = softplus(h @ toU_w + toU_b), K=32
__global__ __launch_bounds__(256) void out_kernel(
    const float* __restrict__ h, const float* __restrict__ tw,
    const float* __restrict__ tb, float* __restrict__ U, int N) {
    int gid = blockIdx.x * blockDim.x + threadIdx.x;
    int n = gid >> 5;
    int k = gid & 31;
    if (n >= N) return;
    float acc = tb[k];
    const float* hr = h + (size_t)n * 64;
    #pragma unroll 8
    for (int j = 0; j < 64; ++j) acc = fmaf(hr[j], tw[j * 32 + k], acc);
    float sp = acc > 0.f ? acc + log1pf(__expf(-acc)) : log1pf(__expf(acc));
    U[(size_t)n * 32 + k] = sp;
}

extern "C" void kernel_launch(void* const* d_in, const int* in_sizes, int n_in,
                              void* d_out, int out_size, void* d_ws, size_t ws_size,
                              hipStream_t stream) {
    const float* x       = (const float*)d_in[0];
    const int*   src     = (const int*)d_in[1];
    const int*   dst     = (const int*)d_in[2];
    const float* base_w  = (const float*)d_in[3];
    const float* enc_w1  = (const float*)d_in[4];
    const float* enc_b1  = (const float*)d_in[5];
    const float* enc_w2  = (const float*)d_in[6];
    const float* enc_b2  = (const float*)d_in[7];
    const float* gate_w1 = (const float*)d_in[8];
    const float* gate_b1 = (const float*)d_in[9];
    const float* gate_w2 = (const float*)d_in[10];
    const float* gate_b2 = (const float*)d_in[11];
    const float* upd_w1  = (const float*)d_in[12];
    const float* upd_b1  = (const float*)d_in[13];
    const float* upd_w2  = (const float*)d_in[14];
    const float* upd_b2  = (const float*)d_in[15];
    const float* ln_g    = (const float*)d_in[16];
    const float* ln_b    = (const float*)d_in[17];
    const float* rho_raw = (const float*)d_in[18];
    const float* toU_w   = (const float*)d_in[19];
    const float* toU_b   = (const float*)d_in[20];

    const int N = in_sizes[18];          // 50000
    const int C = in_sizes[0] / N;       // 256
    const int E = in_sizes[1];           // 800000
    const int L = 2;

    // workspace layout (float units), sections padded to 16B alignment
    float* ws  = (float*)d_ws;
    size_t off = 0;
    float* h0  = ws + off; off += (size_t)N * 64;
    float* h1  = ws + off; off += (size_t)N * 64;
    ushort_t* hb0 = (ushort_t*)(ws + off); off += (size_t)N * 32;
    ushort_t* hb1 = (ushort_t*)(ws + off); off += (size_t)N * 32;
    ushort_t* ab  = (ushort_t*)(ws + off); off += (size_t)N * 32;
    float* bb  = ws + off; off += (size_t)N * 64;
    int* row_ptr = (int*)(ws + off); off += (size_t)((N + 1 + 3) & ~3);
    int* cnt     = (int*)(ws + off); off += (size_t)((N + 3) & ~3);
    int4* recs   = (int4*)(ws + off); off += (size_t)E * 4;   // (s,d,c,0)
    int2* sw     = (int2*)(ws + off); off += (size_t)E * 2;   // (s,w)

    // encoder (+ fused layer-0 gate projection)
    enc_kernel<<<1563, 256, 0, stream>>>(x, enc_w1, enc_b1, enc_w2, enc_b2,
                                         gate_w1, gate_b1,
                                         h0, hb0, ab, bb, N, C);

    // CSR build (dst-sorted edge records); rho folded into scatter
    hipMemsetAsync(cnt, 0, (size_t)N * sizeof(int), stream);
    hist_kernel<<<(E + 255) / 256, 256, 0, stream>>>(dst, cnt, E);
    scan_kernel<<<1, 1024, 0, stream>>>(cnt, row_ptr, N);
    hipMemsetAsync(cnt, 0, (size_t)N * sizeof(int), stream);
    scatter_kernel<<<(E + 255) / 256, 256, 0, stream>>>(src, dst, base_w, rho_raw,
                                                        row_ptr, cnt, recs, E);

    float* h_cur = h0;  ushort_t* hb_cur = hb0;
    float* h_nxt = h1;  ushort_t* hb_nxt = hb1;
    for (int l = 0; l < L; ++l) {
        if (l > 0)  // layer-0 projection came fused from enc
            gateproj_kernel<<<1024, 256, 0, stream>>>(h_cur, gate_w1, gate_b1,
                                                      ab, bb, N);
        gate_kernel<<<4096, 256, 0, stream>>>(recs, ab, bb, gate_w2, gate_b2, sw, E);
        agg_update_kernel<<<2048, 256, 0, stream>>>(
            row_ptr, sw, hb_cur, h_cur,
            upd_w1 + (size_t)l * 4096, upd_b1 + l * 64,
            upd_w2 + (size_t)l * 4096, upd_b2 + l * 64,
            ln_g + l * 64, ln_b + l * 64, h_nxt, hb_nxt, N);
        float* tf = h_cur; h_cur = h_nxt; h_nxt = tf;
        ushort_t* tb2 = hb_cur; hb_cur = hb_nxt; hb_nxt = tb2;
    }

    out_kernel<<<((N * 32) + 255) / 256, 256, 0, stream>>>(h_cur, toU_w, toU_b,
                                                           (float*)d_out, N);
}

// Round 7
// 772.435 us; speedup vs baseline: 2.9676x; 1.6361x over previous
//
#include <hip/hip_runtime.h>
#include <math.h>

// ---------------------------------------------------------------------------
// StageA GNN: encoder -> CSR build -> L x (gateproj, gate, agg+update+LN) -> head
// R7: de-fuse everything that blew registers. enc = lean 4-row/wave, no LDS,
// no epilogue (R6's fused enc hit 256 VGPR + 150MB spill traffic).
// gateproj standalone for BOTH layers. agg_update stays lean (R6 version).
// Rule learned: keep every latency-bound kernel under ~128 VGPR.
// ---------------------------------------------------------------------------

typedef unsigned short ushort_t;

__device__ __forceinline__ float bf2f(ushort_t u) {
    return __uint_as_float(((unsigned int)u) << 16);
}
__device__ __forceinline__ ushort_t f2bf(float f) {
    unsigned int x = __float_as_uint(f);
    unsigned int lsb = (x >> 16) & 1u;
    x += 0x7fffu + lsb;                 // round-to-nearest-even
    return (ushort_t)(x >> 16);
}

__device__ __forceinline__ float wave_sum64(float v) {
    #pragma unroll
    for (int o = 32; o > 0; o >>= 1) v += __shfl_xor(v, o, 64);
    return v;
}

// h = relu(relu(x@W1+b1)@W2+b2); 4 rows/wave, weights via L1/L2, no LDS.
__global__ __launch_bounds__(256) void enc_kernel(
    const float* __restrict__ x, const float* __restrict__ w1,
    const float* __restrict__ b1, const float* __restrict__ w2,
    const float* __restrict__ b2,
    float* __restrict__ h, ushort_t* __restrict__ hb, int N, int C) {
    const int lane = threadIdx.x & 63;
    const int wid  = blockIdx.x * (blockDim.x >> 6) + (threadIdx.x >> 6);
    const int nw   = gridDim.x * (blockDim.x >> 6);
    const float b1l = b1[lane], b2l = b2[lane];
    const int nquad = (N + 3) >> 2;
    for (int q = wid; q < nquad; q += nw) {
        const int r0 = q * 4;
        if (r0 + 3 < N) {
            const float* xr = x + (size_t)r0 * C;
            float s0 = 0.f, s1 = 0.f, s2 = 0.f, s3 = 0.f;
            for (int k4 = 0; k4 < C / 4; ++k4) {
                const float* wp = w1 + (size_t)k4 * 256 + lane;
                float wa = wp[0], wbv = wp[64], wc = wp[128], wd = wp[192];
                float4 v0 = *(const float4*)(xr + k4 * 4);
                float4 v1 = *(const float4*)(xr + (size_t)C + k4 * 4);
                float4 v2 = *(const float4*)(xr + (size_t)2 * C + k4 * 4);
                float4 v3 = *(const float4*)(xr + (size_t)3 * C + k4 * 4);
                s0 = fmaf(wa, v0.x, s0); s0 = fmaf(wbv, v0.y, s0);
                s0 = fmaf(wc, v0.z, s0); s0 = fmaf(wd, v0.w, s0);
                s1 = fmaf(wa, v1.x, s1); s1 = fmaf(wbv, v1.y, s1);
                s1 = fmaf(wc, v1.z, s1); s1 = fmaf(wd, v1.w, s1);
                s2 = fmaf(wa, v2.x, s2); s2 = fmaf(wbv, v2.y, s2);
                s2 = fmaf(wc, v2.z, s2); s2 = fmaf(wd, v2.w, s2);
                s3 = fmaf(wa, v3.x, s3); s3 = fmaf(wbv, v3.y, s3);
                s3 = fmaf(wc, v3.z, s3); s3 = fmaf(wd, v3.w, s3);
            }
            float t0 = fmaxf(s0 + b1l, 0.f), t1 = fmaxf(s1 + b1l, 0.f);
            float t2 = fmaxf(s2 + b1l, 0.f), t3 = fmaxf(s3 + b1l, 0.f);
            float c0 = 0.f, c1 = 0.f, c2 = 0.f, c3 = 0.f;
            #pragma unroll
            for (int k = 0; k < 64; ++k) {
                float wv = w2[(size_t)k * 64 + lane];
                c0 = fmaf(wv, __shfl(t0, k, 64), c0);
                c1 = fmaf(wv, __shfl(t1, k, 64), c1);
                c2 = fmaf(wv, __shfl(t2, k, 64), c2);
                c3 = fmaf(wv, __shfl(t3, k, 64), c3);
            }
            float h0 = fmaxf(c0 + b2l, 0.f), h1 = fmaxf(c1 + b2l, 0.f);
            float h2 = fmaxf(c2 + b2l, 0.f), h3 = fmaxf(c3 + b2l, 0.f);
            h[(size_t)(r0 + 0) * 64 + lane] = h0;
            h[(size_t)(r0 + 1) * 64 + lane] = h1;
            h[(size_t)(r0 + 2) * 64 + lane] = h2;
            h[(size_t)(r0 + 3) * 64 + lane] = h3;
            hb[(size_t)(r0 + 0) * 64 + lane] = f2bf(h0);
            hb[(size_t)(r0 + 1) * 64 + lane] = f2bf(h1);
            hb[(size_t)(r0 + 2) * 64 + lane] = f2bf(h2);
            hb[(size_t)(r0 + 3) * 64 + lane] = f2bf(h3);
        } else {
            for (int r = r0; r < N; ++r) {
                const float* xr = x + (size_t)r * C;
                float acc = 0.f;
                for (int k4 = 0; k4 < C / 4; ++k4) {
                    const float* wp = w1 + (size_t)k4 * 256 + lane;
                    float4 v = *(const float4*)(xr + k4 * 4);
                    acc = fmaf(wp[0],   v.x, acc);
                    acc = fmaf(wp[64],  v.y, acc);
                    acc = fmaf(wp[128], v.z, acc);
                    acc = fmaf(wp[192], v.w, acc);
                }
                float t = fmaxf(acc + b1l, 0.f);
                float acc2 = 0.f;
                #pragma unroll
                for (int k = 0; k < 64; ++k)
                    acc2 = fmaf(w2[(size_t)k * 64 + lane], __shfl(t, k, 64), acc2);
                float hv = fmaxf(acc2 + b2l, 0.f);
                h[(size_t)r * 64 + lane] = hv;
                hb[(size_t)r * 64 + lane] = f2bf(hv);
            }
        }
    }
}

// ---- CSR build (once per call, reused by both layers) ----
__global__ __launch_bounds__(256) void hist_kernel(
    const int* __restrict__ dst, int* __restrict__ cnt, int E) {
    for (int e = blockIdx.x * blockDim.x + threadIdx.x; e < E;
         e += gridDim.x * blockDim.x)
        atomicAdd(&cnt[dst[e]], 1);
}

// single-block exclusive scan: cnt[N] -> row_ptr[N+1]
__global__ __launch_bounds__(1024) void scan_kernel(
    const int* __restrict__ cnt, int* __restrict__ row_ptr, int N) {
    __shared__ int sums[1024];
    const int tid = threadIdx.x;
    const int chunk = (N + 1023) / 1024;
    const int beg = tid * chunk;
    const int end = min(beg + chunk, N);
    int s = 0;
    for (int i = beg; i < end; ++i) s += cnt[i];
    sums[tid] = s;
    __syncthreads();
    for (int off = 1; off < 1024; off <<= 1) {
        int v = (tid >= off) ? sums[tid - off] : 0;
        __syncthreads();
        sums[tid] += v;
        __syncthreads();
    }
    int run = (tid == 0) ? 0 : sums[tid - 1];
    for (int i = beg; i < end; ++i) {
        row_ptr[i] = run;
        run += cnt[i];
    }
    if (tid == 1023) row_ptr[N] = sums[1023];
}

// fill dst-grouped records: (src, dst, base_w*sig(rr_s)*sig(rr_d), pad)
__global__ __launch_bounds__(256) void scatter_kernel(
    const int* __restrict__ src, const int* __restrict__ dst,
    const float* __restrict__ base_w, const float* __restrict__ rr,
    const int* __restrict__ row_ptr, int* __restrict__ fill,
    int4* __restrict__ recs, int E) {
    for (int e = blockIdx.x * blockDim.x + threadIdx.x; e < E;
         e += gridDim.x * blockDim.x) {
        int s = src[e], d = dst[e];
        int pos = row_ptr[d] + atomicAdd(&fill[d], 1);
        float rs = 1.f / (1.f + __expf(-rr[s]));
        float rd = 1.f / (1.f + __expf(-rr[d]));
        float c = base_w[e] * rs * rd;
        recs[pos] = make_int4(s, d, __float_as_int(c), 0);
    }
}

// gate projection: ab = bf16(h@gw1[0:64]+gb1), bbuf = h@gw1[64:128]; no LDS.
__global__ __launch_bounds__(256) void gateproj_kernel(
    const float* __restrict__ h, const float* __restrict__ gw1,
    const float* __restrict__ gb1, ushort_t* __restrict__ ab,
    float* __restrict__ bbuf, int N) {
    const int lane = threadIdx.x & 63;
    const int wid  = blockIdx.x * (blockDim.x >> 6) + (threadIdx.x >> 6);
    const int nw   = gridDim.x * (blockDim.x >> 6);
    const float gbl = gb1[lane];
    for (int r = wid; r < N; r += nw) {
        float hv = h[(size_t)r * 64 + lane];
        float aa = 0.f, bv = 0.f;
        #pragma unroll
        for (int k = 0; k < 64; ++k) {
            float tv = __shfl(hv, k, 64);
            aa = fmaf(gw1[(size_t)k * 64 + lane], tv, aa);
            bv = fmaf(gw1[(size_t)(64 + k) * 64 + lane], tv, bv);
        }
        ab[(size_t)r * 64 + lane] = f2bf(aa + gbl);
        bbuf[(size_t)r * 64 + lane] = bv;
    }
}

// 16 lanes per edge: z = relu(a[s]+bb[d]) dot gw2 (4 elems/lane, 4-step reduce)
// w = c * sigmoid(z + gb2);  sw[e] = (s, w).  a gathered as bf16 (8B/lane).
__global__ __launch_bounds__(256) void gate_kernel(
    const int4* __restrict__ recs, const ushort_t* __restrict__ ab,
    const float* __restrict__ bb, const float* __restrict__ gw2,
    const float* __restrict__ gb2, int2* __restrict__ sw, int E) {
    const int lane = threadIdx.x & 63;
    const int sub  = lane & 15;                       // feature slice id
    const float4 gv = ((const float4*)gw2)[sub];
    const float gb = gb2[0];
    int grp  = (blockIdx.x * blockDim.x + threadIdx.x) >> 4;
    const int ngrp = (gridDim.x * blockDim.x) >> 4;
    for (int e = grp; e < E; e += ngrp) {
        int4 r = recs[e];                             // broadcast within group
        ushort4 av = ((const ushort4*)(ab + (size_t)r.x * 64))[sub];
        float4 bv = ((const float4*)(bb + (size_t)r.y * 64))[sub];
        float t = fmaxf(bf2f(av.x) + bv.x, 0.f) * gv.x
                + fmaxf(bf2f(av.y) + bv.y, 0.f) * gv.y
                + fmaxf(bf2f(av.z) + bv.z, 0.f) * gv.z
                + fmaxf(bf2f(av.w) + bv.w, 0.f) * gv.w;
        #pragma unroll
        for (int o = 8; o > 0; o >>= 1) t += __shfl_xor(t, o, 64);
        float w = __int_as_float(r.z) / (1.f + __expf(-(t + gb)));
        if (sub == 0) sw[e] = make_int2(r.x, __float_as_int(w));
    }
}

// wave-per-node: gather+fma aggregation over bf16 h rows (8-deep unroll, no
// cross-lane ops in loop), fused update MLP + LayerNorm in fp32.
// Weights read from global (L1-resident) -> no LDS, no barrier.
__global__ __launch_bounds__(256) void agg_update_kernel(
    const int* __restrict__ row_ptr, const int2* __restrict__ sw,
    const ushort_t* __restrict__ hb_in, const float* __restrict__ h_in,
    const float* __restrict__ w1, const float* __restrict__ b1,
    const float* __restrict__ w2, const float* __restrict__ b2,
    const float* __restrict__ lng, const float* __restrict__ lnb,
    float* __restrict__ h_out, ushort_t* __restrict__ hb_out, int N) {
    const int lane = threadIdx.x & 63;
    const int wid  = blockIdx.x * (blockDim.x >> 6) + (threadIdx.x >> 6);
    const int nw   = gridDim.x * (blockDim.x >> 6);
    const float b1l = b1[lane], b2l = b2[lane];
    const float gl = lng[lane], bl = lnb[lane];
    for (int n = wid; n < N; n += nw) {
        const int beg = row_ptr[n], end = row_ptr[n + 1];
        float macc = 0.f, dacc = 0.f;
        int i = beg;
        for (; i + 8 <= end; i += 8) {
            int2 r0 = sw[i],     r1 = sw[i + 1], r2 = sw[i + 2], r3 = sw[i + 3];
            int2 r4 = sw[i + 4], r5 = sw[i + 5], r6 = sw[i + 6], r7 = sw[i + 7];
            float hv0 = bf2f(hb_in[(size_t)r0.x * 64 + lane]);
            float hv1 = bf2f(hb_in[(size_t)r1.x * 64 + lane]);
            float hv2 = bf2f(hb_in[(size_t)r2.x * 64 + lane]);
            float hv3 = bf2f(hb_in[(size_t)r3.x * 64 + lane]);
            float hv4 = bf2f(hb_in[(size_t)r4.x * 64 + lane]);
            float hv5 = bf2f(hb_in[(size_t)r5.x * 64 + lane]);
            float hv6 = bf2f(hb_in[(size_t)r6.x * 64 + lane]);
            float hv7 = bf2f(hb_in[(size_t)r7.x * 64 + lane]);
            float w0 = __int_as_float(r0.y), w1v = __int_as_float(r1.y);
            float w2v = __int_as_float(r2.y), w3v = __int_as_float(r3.y);
            float w4v = __int_as_float(r4.y), w5v = __int_as_float(r5.y);
            float w6v = __int_as_float(r6.y), w7v = __int_as_float(r7.y);
            macc = fmaf(w0, hv0, macc);  macc = fmaf(w1v, hv1, macc);
            macc = fmaf(w2v, hv2, macc); macc = fmaf(w3v, hv3, macc);
            macc = fmaf(w4v, hv4, macc); macc = fmaf(w5v, hv5, macc);
            macc = fmaf(w6v, hv6, macc); macc = fmaf(w7v, hv7, macc);
            dacc += ((w0 + w1v) + (w2v + w3v)) + ((w4v + w5v) + (w6v + w7v));
        }
        for (; i < end; ++i) {
            int2 r0 = sw[i];
            float hv0 = bf2f(hb_in[(size_t)r0.x * 64 + lane]);
            float w0 = __int_as_float(r0.y);
            macc = fmaf(w0, hv0, macc);
            dacc += w0;
        }
        // ---- fused update MLP + LayerNorm ----
        float neigh = macc / (dacc + 1e-8f);
        float acc = 0.f;
        #pragma unroll
        for (int k = 0; k < 64; ++k) {
            float tv = __shfl(neigh, k, 64);
            acc = fmaf(w1[(size_t)k * 64 + lane], tv, acc);
        }
        float t = fmaxf(acc + b1l, 0.f);
        float acc2 = 0.f;
        #pragma unroll
        for (int k = 0; k < 64; ++k) {
            float tv = __shfl(t, k, 64);
            acc2 = fmaf(w2[(size_t)k * 64 + lane], tv, acc2);
        }
        float pre = h_in[(size_t)n * 64 + lane] + acc2 + b2l;
        float s1 = wave_sum64(pre);
        float s2 = wave_sum64(pre * pre);
        float mean = s1 * (1.0f / 64.0f);
        float var  = s2 * (1.0f / 64.0f) - mean * mean;
        float hn = (pre - mean) * rsqrtf(var + 1e-5f) * gl + bl;
        h_out[(size_t)n * 64 + lane] = hn;
        hb_out[(size_t)n * 64 + lane] = f2bf(hn);
    }
}

// U = softplus(h @ toU_w + toU_b), K=32
__global__ __launch_bounds__(256) void out_kernel(
    const float* __restrict__ h, const float* __restrict__ tw,
    const float* __restrict__ tb, float* __restrict__ U, int N) {
    int gid = blockIdx.x * blockDim.x + threadIdx.x;
    int n = gid >> 5;
    int k = gid & 31;
    if (n >= N) return;
    float acc = tb[k];
    const float* hr = h + (size_t)n * 64;
    #pragma unroll 8
    for (int j = 0; j < 64; ++j) acc = fmaf(hr[j], tw[j * 32 + k], acc);
    float sp = acc > 0.f ? acc + log1pf(__expf(-acc)) : log1pf(__expf(acc));
    U[(size_t)n * 32 + k] = sp;
}

extern "C" void kernel_launch(void* const* d_in, const int* in_sizes, int n_in,
                              void* d_out, int out_size, void* d_ws, size_t ws_size,
                              hipStream_t stream) {
    const float* x       = (const float*)d_in[0];
    const int*   src     = (const int*)d_in[1];
    const int*   dst     = (const int*)d_in[2];
    const float* base_w  = (const float*)d_in[3];
    const float* enc_w1  = (const float*)d_in[4];
    const float* enc_b1  = (const float*)d_in[5];
    const float* enc_w2  = (const float*)d_in[6];
    const float* enc_b2  = (const float*)d_in[7];
    const float* gate_w1 = (const float*)d_in[8];
    const float* gate_b1 = (const float*)d_in[9];
    const float* gate_w2 = (const float*)d_in[10];
    const float* gate_b2 = (const float*)d_in[11];
    const float* upd_w1  = (const float*)d_in[12];
    const float* upd_b1  = (const float*)d_in[13];
    const float* upd_w2  = (const float*)d_in[14];
    const float* upd_b2  = (const float*)d_in[15];
    const float* ln_g    = (const float*)d_in[16];
    const float* ln_b    = (const float*)d_in[17];
    const float* rho_raw = (const float*)d_in[18];
    const float* toU_w   = (const float*)d_in[19];
    const float* toU_b   = (const float*)d_in[20];

    const int N = in_sizes[18];          // 50000
    const int C = in_sizes[0] / N;       // 256
    const int E = in_sizes[1];           // 800000
    const int L = 2;

    // workspace layout (float units), sections padded to 16B alignment
    float* ws  = (float*)d_ws;
    size_t off = 0;
    float* h0  = ws + off; off += (size_t)N * 64;
    float* h1  = ws + off; off += (size_t)N * 64;
    ushort_t* hb0 = (ushort_t*)(ws + off); off += (size_t)N * 32;
    ushort_t* hb1 = (ushort_t*)(ws + off); off += (size_t)N * 32;
    ushort_t* ab  = (ushort_t*)(ws + off); off += (size_t)N * 32;
    float* bb  = ws + off; off += (size_t)N * 64;
    int* row_ptr = (int*)(ws + off); off += (size_t)((N + 1 + 3) & ~3);
    int* cnt     = (int*)(ws + off); off += (size_t)((N + 3) & ~3);
    int4* recs   = (int4*)(ws + off); off += (size_t)E * 4;   // (s,d,c,0)
    int2* sw     = (int2*)(ws + off); off += (size_t)E * 2;   // (s,w)

    enc_kernel<<<1563, 256, 0, stream>>>(x, enc_w1, enc_b1, enc_w2, enc_b2,
                                         h0, hb0, N, C);

    // CSR build (dst-sorted edge records); rho folded into scatter
    hipMemsetAsync(cnt, 0, (size_t)N * sizeof(int), stream);
    hist_kernel<<<(E + 255) / 256, 256, 0, stream>>>(dst, cnt, E);
    scan_kernel<<<1, 1024, 0, stream>>>(cnt, row_ptr, N);
    hipMemsetAsync(cnt, 0, (size_t)N * sizeof(int), stream);
    scatter_kernel<<<(E + 255) / 256, 256, 0, stream>>>(src, dst, base_w, rho_raw,
                                                        row_ptr, cnt, recs, E);

    float* h_cur = h0;  ushort_t* hb_cur = hb0;
    float* h_nxt = h1;  ushort_t* hb_nxt = hb1;
    for (int l = 0; l < L; ++l) {
        gateproj_kernel<<<1024, 256, 0, stream>>>(h_cur, gate_w1, gate_b1,
                                                  ab, bb, N);
        gate_kernel<<<4096, 256, 0, stream>>>(recs, ab, bb, gate_w2, gate_b2, sw, E);
        agg_update_kernel<<<2048, 256, 0, stream>>>(
            row_ptr, sw, hb_cur, h_cur,
            upd_w1 + (size_t)l * 4096, upd_b1 + l * 64,
            upd_w2 + (size_t)l * 4096, upd_b2 + l * 64,
            ln_g + l * 64, ln_b + l * 64, h_nxt, hb_nxt, N);
        float* tf = h_cur; h_cur = h_nxt; h_nxt = tf;
        ushort_t* tb2 = hb_cur; hb_cur = hb_nxt; hb_nxt = tb2;
    }

    out_kernel<<<((N * 32) + 255) / 256, 256, 0, stream>>>(h_cur, toU_w, toU_b,
                                                           (float*)d_out, N);
}